// Round 5
// baseline (215.473 us; speedup 1.0000x reference)
//
#include <hip/hip_runtime.h>
#include <hip/hip_bf16.h>

#define NB 2
#define NS 2048
#define NDM 1024
#define NH 16
#define ND 64
#define NM (NB * NS)   // 4096
#define RS 3072        // qkv row stride
#define C1 0.1803368801111243f   // SCALE * log2(e)
#define THR_RAW 44.36141956f     // 8 / C1 : defer-max threshold in raw-score units

typedef __attribute__((ext_vector_type(8))) short bf16x8;   // MFMA A/B frag (4 VGPRs)
typedef __attribute__((ext_vector_type(4))) float f32x4;    // MFMA C/D frag

__device__ __forceinline__ unsigned short f2bf(float f) {
    unsigned int u = __float_as_uint(f);
    u += 0x7fffu + ((u >> 16) & 1u);   // RNE
    return (unsigned short)(u >> 16);
}

// async global->LDS, 16B per lane. LDS dest = wave-uniform base + lane*16.
__device__ __forceinline__ void gload16(const unsigned short* g, unsigned short* l) {
    __builtin_amdgcn_global_load_lds(
        (const __attribute__((address_space(1))) void*)g,
        (__attribute__((address_space(3))) void*)l, 16, 0, 0);
}

// ---------------------------------------------------------------------------
// fp32 -> bf16 elementwise
// ---------------------------------------------------------------------------
__global__ __launch_bounds__(256)
void convert_bf16(const float* __restrict__ in, unsigned short* __restrict__ out, int n8) {
    int i = blockIdx.x * 256 + threadIdx.x;
    const int stride = gridDim.x * 256;
    for (; i < n8; i += stride) {
        const float4 a = ((const float4*)in)[i * 2];
        const float4 b = ((const float4*)in)[i * 2 + 1];
        bf16x8 v;
        v[0] = (short)f2bf(a.x); v[1] = (short)f2bf(a.y);
        v[2] = (short)f2bf(a.z); v[3] = (short)f2bf(a.w);
        v[4] = (short)f2bf(b.x); v[5] = (short)f2bf(b.y);
        v[6] = (short)f2bf(b.z); v[7] = (short)f2bf(b.w);
        *(bf16x8*)(out + (size_t)i * 8) = v;
    }
}

// ---------------------------------------------------------------------------
// W[K][N] fp32 -> WT[N][K] bf16 (64x64 LDS-tiled)
// ---------------------------------------------------------------------------
__global__ __launch_bounds__(256)
void transpose_bf16(const float* __restrict__ W, unsigned short* __restrict__ WT,
                    int K, int N) {
    __shared__ float Ts[64][65];
    const int n0 = blockIdx.x * 64, k0 = blockIdx.y * 64;
    const int t = threadIdx.x;
    {
        const int c4 = (t & 15) * 4;
        #pragma unroll
        for (int p = 0; p < 4; p++) {
            const int r = (t >> 4) + p * 16;
            const float4 v = *(const float4*)(W + (size_t)(k0 + r) * N + n0 + c4);
            Ts[r][c4] = v.x; Ts[r][c4 + 1] = v.y; Ts[r][c4 + 2] = v.z; Ts[r][c4 + 3] = v.w;
        }
    }
    __syncthreads();
    {
        const int cc8 = (t & 7) * 8;
        #pragma unroll
        for (int p = 0; p < 2; p++) {
            const int rr = (t >> 3) + p * 32;
            bf16x8 v;
            #pragma unroll
            for (int j = 0; j < 8; j++) v[j] = (short)f2bf(Ts[cc8 + j][rr]);
            *(bf16x8*)(WT + (size_t)(n0 + rr) * K + k0 + cc8) = v;
        }
    }
}

// ---------------------------------------------------------------------------
// V columns of qkv [token][3072] -> vT [bh][d=64][s=2048], 64x64 tiles.
// FIX(r4->r5): load BOTH 32-row halves (r and r+32); vectorized store.
// ---------------------------------------------------------------------------
__global__ __launch_bounds__(256)
void vtrans(const unsigned short* __restrict__ qkvb, unsigned short* __restrict__ vT) {
    __shared__ unsigned short Ts[64][65];
    const int st = blockIdx.x, bh = blockIdx.y;
    const int h = bh & (NH - 1), b = bh >> 4;
    const int t = threadIdx.x;
    {
        const int c8 = (t & 7) * 8;
        #pragma unroll
        for (int p = 0; p < 2; p++) {
            const int r = (t >> 3) + p * 32;
            const unsigned short* src =
                qkvb + (size_t)(b * NS + st * 64 + r) * RS + 2 * NDM + h * ND + c8;
            const bf16x8 v = *(const bf16x8*)src;
            #pragma unroll
            for (int j = 0; j < 8; j++) Ts[r][c8 + j] = (unsigned short)v[j];
        }
    }
    __syncthreads();
    {
        #pragma unroll
        for (int i = 0; i < 2; i++) {
            const int u = t + i * 256;
            const int d = u >> 3, cg = (u & 7) * 8;
            bf16x8 v;
            #pragma unroll
            for (int j = 0; j < 8; j++) v[j] = (short)Ts[cg + j][d];
            *(bf16x8*)(vT + ((size_t)bh * ND + d) * NS + st * 64 + cg) = v;
        }
    }
}

// ---------------------------------------------------------------------------
// m97-style 128x128 GEMM, BK=32, global_load_lds(16B) with swizzled source.
// A[M,K] bf16, BT[N,K] bf16. MODE 0: fp32 C + bias. MODE 1: bf16 C + bias.
// ---------------------------------------------------------------------------
template<int MODE>
__global__ __launch_bounds__(256)
void gemm128(const unsigned short* __restrict__ A, const unsigned short* __restrict__ BT,
             const float* __restrict__ bias, void* __restrict__ Cv,
             int M, int N, int K) {
    __shared__ unsigned short As[128 * 32];   // 8 KB
    __shared__ unsigned short Bs[128 * 32];   // 8 KB

    const int t = threadIdx.x, lane = t & 63, wv = t >> 6;
    const int wm = wv >> 1, wn = wv & 1;
    const int m0 = blockIdx.y * 128, n0 = blockIdx.x * 128;
    const int fr = lane & 15, fg = lane >> 4;

    f32x4 acc[4][4];
    #pragma unroll
    for (int m = 0; m < 4; m++)
        #pragma unroll
        for (int n = 0; n < 4; n++)
            #pragma unroll
            for (int r = 0; r < 4; r++) acc[m][n][r] = 0.f;

    for (int k0 = 0; k0 < K; k0 += 32) {
        __syncthreads();
        #pragma unroll
        for (int i = 0; i < 2; i++) {
            const int u = t + i * 256;
            const int row = u >> 2;
            const int grp = (u & 3) ^ ((row ^ (row >> 2)) & 3);
            gload16(A  + (size_t)(m0 + row) * K + k0 + grp * 8, &As[(i * 256 + wv * 64) * 8]);
            gload16(BT + (size_t)(n0 + row) * K + k0 + grp * 8, &Bs[(i * 256 + wv * 64) * 8]);
        }
        __syncthreads();

        bf16x8 af[4], bfv[4];
        #pragma unroll
        for (int m = 0; m < 4; m++) {
            const int row = wm * 64 + m * 16 + fr;
            af[m] = *(const bf16x8*)&As[row * 32 + (fg ^ ((row ^ (row >> 2)) & 3)) * 8];
        }
        #pragma unroll
        for (int n = 0; n < 4; n++) {
            const int row = wn * 64 + n * 16 + fr;
            bfv[n] = *(const bf16x8*)&Bs[row * 32 + (fg ^ ((row ^ (row >> 2)) & 3)) * 8];
        }
        #pragma unroll
        for (int m = 0; m < 4; m++)
            #pragma unroll
            for (int n = 0; n < 4; n++)
                acc[m][n] = __builtin_amdgcn_mfma_f32_16x16x32_bf16(
                    af[m], bfv[n], acc[m][n], 0, 0, 0);
    }

    #pragma unroll
    for (int m = 0; m < 4; m++)
        #pragma unroll
        for (int n = 0; n < 4; n++) {
            const int col = n0 + wn * 64 + n * 16 + fr;
            const float bb = bias[col];
            #pragma unroll
            for (int rg = 0; rg < 4; rg++) {
                const int row = m0 + wm * 64 + m * 16 + fg * 4 + rg;
                const float v = acc[m][n][rg] + bb;
                if (MODE == 0) ((float*)Cv)[(size_t)row * N + col] = v;
                else ((unsigned short*)Cv)[(size_t)row * N + col] = f2bf(v);
            }
        }
}

// ---------------------------------------------------------------------------
// Causal MFMA flash attention, 2-phase double-buffered staging.
// qkv bf16 [token][3072] (q at h*64, k at 1024+h*64), vT bf16 [bh][d][s].
// Block = 64 q rows (4 waves x 16), KVBLK = 64, LPT order (qt descending).
// LDS 40KB -> 4 blocks/CU. One barrier per KV tile.
// ---------------------------------------------------------------------------
__global__ __launch_bounds__(256)
void attn_mfma(const unsigned short* __restrict__ qkvb, const unsigned short* __restrict__ vT,
               unsigned short* __restrict__ atto) {
    const int bx = blockIdx.x;
    const int qt = (NS / 64 - 1) - (bx >> 5);   // 31..0 (longest first)
    const int bh = bx & 31;
    const int h = bh & (NH - 1), b = bh >> 4;
    const int q0 = qt * 64;
    const int t = threadIdx.x, lane = t & 63, wv = t >> 6;
    const int fr = lane & 15, fg = lane >> 4;

    __shared__ unsigned short Kt[2][64 * 64];   // 16 KB
    __shared__ unsigned short Vt[2][64 * 64];   // 16 KB
    __shared__ unsigned short Ps[4][16 * 64];   //  8 KB, wave-private

    const unsigned short* kb = qkvb + (size_t)b * NS * RS + NDM + h * ND;
    const unsigned short* vb = vT + (size_t)bh * ND * NS;

    // Q fragments straight from global
    bf16x8 qf[2];
    {
        const unsigned short* qrow =
            qkvb + (size_t)(b * NS + q0 + wv * 16 + fr) * RS + h * ND;
        qf[0] = *(const bf16x8*)(qrow + fg * 8);
        qf[1] = *(const bf16x8*)(qrow + 32 + fg * 8);
    }

    f32x4 oacc[4];
    #pragma unroll
    for (int d = 0; d < 4; d++)
        #pragma unroll
        for (int r = 0; r < 4; r++) oacc[d][r] = 0.f;
    float mrow[4] = {-INFINITY, -INFINITY, -INFINITY, -INFINITY};
    float nmC[4]  = {INFINITY, INFINITY, INFINITY, INFINITY};    // -mrow*C1
    float lrow[4] = {0.f, 0.f, 0.f, 0.f};

    const int ntiles = qt + 1;

#define STAGE_KV(cbuf, jtile)                                                        \
    {                                                                                \
        _Pragma("unroll")                                                            \
        for (int i = 0; i < 2; i++) {                                                \
            const int u = t + i * 256;                                               \
            const int row = u >> 3;                                                  \
            const int grp = (u & 7) ^ (row & 7);                                     \
            gload16(kb + (size_t)((jtile) * 64 + row) * RS + grp * 8,                \
                    &Kt[cbuf][(i * 256 + wv * 64) * 8]);                             \
        }                                                                            \
        _Pragma("unroll")                                                            \
        for (int i = 0; i < 2; i++) {                                                \
            const int u = t + i * 256;                                               \
            const int row = u >> 3;                                                  \
            const int grp = (u & 7) ^ (row & 7);                                     \
            gload16(vb + (size_t)row * NS + (jtile) * 64 + grp * 8,                  \
                    &Vt[cbuf][(i * 256 + wv * 64) * 8]);                             \
        }                                                                            \
    }

    STAGE_KV(0, 0);

    for (int jt = 0; jt < ntiles; jt++) {
        const int cur = jt & 1;
        __syncthreads();   // drains vmcnt (stage of cur done) + read-fence on cur^1
        if (jt + 1 < ntiles) STAGE_KV(cur ^ 1, jt + 1);

        // ---- S = Q K^T : 4 key-blocks x 2 k-halves
        f32x4 sacc[4];
        __builtin_amdgcn_s_setprio(1);
        #pragma unroll
        for (int kbi = 0; kbi < 4; kbi++) {
            #pragma unroll
            for (int r = 0; r < 4; r++) sacc[kbi][r] = 0.f;
            const int row = kbi * 16 + fr;
            const bf16x8 kf0 = *(const bf16x8*)&Kt[cur][row * 64 + ((fg) ^ (row & 7)) * 8];
            const bf16x8 kf1 = *(const bf16x8*)&Kt[cur][row * 64 + ((4 + fg) ^ (row & 7)) * 8];
            sacc[kbi] = __builtin_amdgcn_mfma_f32_16x16x32_bf16(qf[0], kf0, sacc[kbi], 0, 0, 0);
            sacc[kbi] = __builtin_amdgcn_mfma_f32_16x16x32_bf16(qf[1], kf1, sacc[kbi], 0, 0, 0);
        }
        __builtin_amdgcn_s_setprio(0);

        if (jt == ntiles - 1) {   // diagonal tile: causal mask (raw domain)
            #pragma unroll
            for (int kbi = 0; kbi < 4; kbi++) {
                const int keyg = jt * 64 + kbi * 16 + fr;
                #pragma unroll
                for (int reg = 0; reg < 4; reg++) {
                    const int qg = q0 + wv * 16 + fg * 4 + reg;
                    if (keyg > qg) sacc[kbi][reg] = -INFINITY;
                }
            }
        }

        // ---- online softmax (exp2 domain, defer-max)
        float pmax[4];
        #pragma unroll
        for (int reg = 0; reg < 4; reg++) {
            float pm = fmaxf(fmaxf(sacc[0][reg], sacc[1][reg]),
                             fmaxf(sacc[2][reg], sacc[3][reg]));
            pm = fmaxf(pm, __shfl_xor(pm, 1));
            pm = fmaxf(pm, __shfl_xor(pm, 2));
            pm = fmaxf(pm, __shfl_xor(pm, 4));
            pm = fmaxf(pm, __shfl_xor(pm, 8));
            pmax[reg] = pm;
        }
        bool need = false;
        #pragma unroll
        for (int reg = 0; reg < 4; reg++) need |= (pmax[reg] > mrow[reg] + THR_RAW);
        if (__any(need)) {
            #pragma unroll
            for (int reg = 0; reg < 4; reg++) {
                const float mn = fmaxf(mrow[reg], pmax[reg]);
                const float alpha = __builtin_amdgcn_exp2f((mrow[reg] - mn) * C1);
                mrow[reg] = mn;
                nmC[reg] = -mn * C1;
                lrow[reg] *= alpha;
                #pragma unroll
                for (int dblk = 0; dblk < 4; dblk++) oacc[dblk][reg] *= alpha;
            }
        }
        #pragma unroll
        for (int reg = 0; reg < 4; reg++) {
            float ps = 0.f;
            #pragma unroll
            for (int kbi = 0; kbi < 4; kbi++) {
                const float p = __builtin_amdgcn_exp2f(fmaf(sacc[kbi][reg], C1, nmC[reg]));
                sacc[kbi][reg] = p;
                ps += p;
            }
            ps += __shfl_xor(ps, 1);
            ps += __shfl_xor(ps, 2);
            ps += __shfl_xor(ps, 4);
            ps += __shfl_xor(ps, 8);
            lrow[reg] += ps;
        }

        // ---- P -> wave-private LDS (swizzled)
        #pragma unroll
        for (int kbi = 0; kbi < 4; kbi++) {
            const int colk = kbi * 16 + fr;
            #pragma unroll
            for (int reg = 0; reg < 4; reg++) {
                const int prow = fg * 4 + reg;
                Ps[wv][prow * 64 + (((colk >> 3) ^ (prow & 7)) << 3) + (colk & 7)] =
                    f2bf(sacc[kbi][reg]);
            }
        }

        // ---- O += P V  (Ps wave-private: in-order ds, no barrier)
        bf16x8 pf[2];
        #pragma unroll
        for (int ks = 0; ks < 2; ks++)
            pf[ks] = *(const bf16x8*)&Ps[wv][fr * 64 + ((ks * 4 + fg) ^ (fr & 7)) * 8];
        __builtin_amdgcn_s_setprio(1);
        #pragma unroll
        for (int dblk = 0; dblk < 4; dblk++) {
            const int vrow = dblk * 16 + fr;
            #pragma unroll
            for (int ks = 0; ks < 2; ks++) {
                const bf16x8 vf =
                    *(const bf16x8*)&Vt[cur][vrow * 64 + ((ks * 4 + fg) ^ (vrow & 7)) * 8];
                oacc[dblk] = __builtin_amdgcn_mfma_f32_16x16x32_bf16(
                    pf[ks], vf, oacc[dblk], 0, 0, 0);
            }
        }
        __builtin_amdgcn_s_setprio(0);
    }
#undef STAGE_KV

    // ---- epilogue
    #pragma unroll
    for (int reg = 0; reg < 4; reg++) {
        const float inv = 1.f / lrow[reg];
        const int row = q0 + wv * 16 + fg * 4 + reg;
        unsigned short* dst = atto + ((size_t)b * NS + row) * NDM + h * ND;
        #pragma unroll
        for (int dblk = 0; dblk < 4; dblk++)
            dst[dblk * 16 + fr] = f2bf(oacc[dblk][reg] * inv);
    }
}

// ---------------------------------------------------------------------------
extern "C" void kernel_launch(void* const* d_in, const int* in_sizes, int n_in,
                              void* d_out, int out_size, void* d_ws, size_t ws_size,
                              hipStream_t stream) {
    const float* x     = (const float*)d_in[0];
    const float* w_qkv = (const float*)d_in[1];
    const float* b_qkv = (const float*)d_in[2];
    const float* w_out = (const float*)d_in[3];
    const float* b_out = (const float*)d_in[4];
    float* out = (float*)d_out;

    unsigned short* xb   = (unsigned short*)d_ws;             //  8 MB [4096][1024] (aliased by atto)
    unsigned short* wqT  = xb   + (size_t)NM * NDM;           //  6 MB [3072][1024]
    unsigned short* woT  = wqT  + (size_t)3 * NDM * NDM;      //  2 MB [1024][1024]
    unsigned short* qkvb = woT  + (size_t)NDM * NDM;          // 24 MB [4096][3072]
    unsigned short* vT   = qkvb + (size_t)NM * 3 * NDM;       //  8 MB [32][64][2048]
    unsigned short* atto = xb;                                //  alias: xb dead after gemm1

    convert_bf16<<<2048, 256, 0, stream>>>(x, xb, NM * NDM / 8);
    transpose_bf16<<<dim3(3 * NDM / 64, NDM / 64), 256, 0, stream>>>(w_qkv, wqT, NDM, 3 * NDM);
    transpose_bf16<<<dim3(NDM / 64, NDM / 64), 256, 0, stream>>>(w_out, woT, NDM, NDM);

    // 1) qkv = x @ w_qkv + b   (bf16, row-major, coalesced)
    gemm128<1><<<dim3(3 * NDM / 128, NM / 128), 256, 0, stream>>>(
        xb, wqT, b_qkv, qkvb, NM, 3 * NDM, NDM);

    // 1b) vT = transpose of v columns
    vtrans<<<dim3(NS / 64, NB * NH), 256, 0, stream>>>(qkvb, vT);

    // 2) causal MFMA flash attention (double-buffered)
    attn_mfma<<<dim3((NS / 64) * NB * NH), 256, 0, stream>>>(qkvb, vT, atto);

    // 3) out = atto @ w_out + b  (fp32 out)
    gemm128<0><<<dim3(NDM / 128, NM / 128), 256, 0, stream>>>(
        atto, woT, b_out, out, NM, NDM, NDM);
}

// Round 6
// 205.892 us; speedup vs baseline: 1.0465x; 1.0465x over previous
//
#include <hip/hip_runtime.h>
#include <hip/hip_bf16.h>

#define NB 2
#define NS 2048
#define NDM 1024
#define NH 16
#define ND 64
#define NM (NB * NS)   // 4096
#define RS 3072        // qkv row stride
#define C1 0.1803368801111243f   // SCALE * log2(e)
#define THR_RAW 44.36141956f     // 8 / C1 : defer-max threshold in raw-score units

typedef __attribute__((ext_vector_type(8))) short bf16x8;   // MFMA A/B frag (4 VGPRs)
typedef __attribute__((ext_vector_type(4))) float f32x4;    // MFMA C/D frag

__device__ __forceinline__ unsigned short f2bf(float f) {
    unsigned int u = __float_as_uint(f);
    u += 0x7fffu + ((u >> 16) & 1u);   // RNE
    return (unsigned short)(u >> 16);
}

// async global->LDS, 16B per lane. LDS dest = wave-uniform base + lane*16.
__device__ __forceinline__ void gload16(const unsigned short* g, unsigned short* l) {
    __builtin_amdgcn_global_load_lds(
        (const __attribute__((address_space(1))) void*)g,
        (__attribute__((address_space(3))) void*)l, 16, 0, 0);
}

// ---------------------------------------------------------------------------
// fp32 -> bf16 elementwise
// ---------------------------------------------------------------------------
__global__ __launch_bounds__(256)
void convert_bf16(const float* __restrict__ in, unsigned short* __restrict__ out, int n8) {
    int i = blockIdx.x * 256 + threadIdx.x;
    const int stride = gridDim.x * 256;
    for (; i < n8; i += stride) {
        const float4 a = ((const float4*)in)[i * 2];
        const float4 b = ((const float4*)in)[i * 2 + 1];
        bf16x8 v;
        v[0] = (short)f2bf(a.x); v[1] = (short)f2bf(a.y);
        v[2] = (short)f2bf(a.z); v[3] = (short)f2bf(a.w);
        v[4] = (short)f2bf(b.x); v[5] = (short)f2bf(b.y);
        v[6] = (short)f2bf(b.z); v[7] = (short)f2bf(b.w);
        *(bf16x8*)(out + (size_t)i * 8) = v;
    }
}

// ---------------------------------------------------------------------------
// W[K][N] fp32 -> WT[N][K] bf16 (64x64 LDS-tiled)
// ---------------------------------------------------------------------------
__global__ __launch_bounds__(256)
void transpose_bf16(const float* __restrict__ W, unsigned short* __restrict__ WT,
                    int K, int N) {
    __shared__ float Ts[64][65];
    const int n0 = blockIdx.x * 64, k0 = blockIdx.y * 64;
    const int t = threadIdx.x;
    {
        const int c4 = (t & 15) * 4;
        #pragma unroll
        for (int p = 0; p < 4; p++) {
            const int r = (t >> 4) + p * 16;
            const float4 v = *(const float4*)(W + (size_t)(k0 + r) * N + n0 + c4);
            Ts[r][c4] = v.x; Ts[r][c4 + 1] = v.y; Ts[r][c4 + 2] = v.z; Ts[r][c4 + 3] = v.w;
        }
    }
    __syncthreads();
    {
        const int cc8 = (t & 7) * 8;
        #pragma unroll
        for (int p = 0; p < 2; p++) {
            const int rr = (t >> 3) + p * 32;
            bf16x8 v;
            #pragma unroll
            for (int j = 0; j < 8; j++) v[j] = (short)f2bf(Ts[cc8 + j][rr]);
            *(bf16x8*)(WT + (size_t)(n0 + rr) * K + k0 + cc8) = v;
        }
    }
}

// ---------------------------------------------------------------------------
// V columns of qkv [token][3072] -> vT [bh][d=64][s=2048], 64x64 tiles.
// ---------------------------------------------------------------------------
__global__ __launch_bounds__(256)
void vtrans(const unsigned short* __restrict__ qkvb, unsigned short* __restrict__ vT) {
    __shared__ unsigned short Ts[64][65];
    const int st = blockIdx.x, bh = blockIdx.y;
    const int h = bh & (NH - 1), b = bh >> 4;
    const int t = threadIdx.x;
    {
        const int c8 = (t & 7) * 8;
        #pragma unroll
        for (int p = 0; p < 2; p++) {
            const int r = (t >> 3) + p * 32;
            const unsigned short* src =
                qkvb + (size_t)(b * NS + st * 64 + r) * RS + 2 * NDM + h * ND + c8;
            const bf16x8 v = *(const bf16x8*)src;
            #pragma unroll
            for (int j = 0; j < 8; j++) Ts[r][c8 + j] = (unsigned short)v[j];
        }
    }
    __syncthreads();
    {
        #pragma unroll
        for (int i = 0; i < 2; i++) {
            const int u = t + i * 256;
            const int d = u >> 3, cg = (u & 7) * 8;
            bf16x8 v;
            #pragma unroll
            for (int j = 0; j < 8; j++) v[j] = (short)Ts[cg + j][d];
            *(bf16x8*)(vT + ((size_t)bh * ND + d) * NS + st * 64 + cg) = v;
        }
    }
}

// ---------------------------------------------------------------------------
// 128x128 GEMM, BK=32, DOUBLE-BUFFERED: 1 barrier per K-step, next tile's
// global_load_lds always in flight under current tile's compute (T3-minimal).
// A[M,K] bf16, BT[N,K] bf16. MODE 0: fp32 C + bias. MODE 1: bf16 C + bias.
// ---------------------------------------------------------------------------
template<int MODE>
__global__ __launch_bounds__(256)
void gemm128(const unsigned short* __restrict__ A, const unsigned short* __restrict__ BT,
             const float* __restrict__ bias, void* __restrict__ Cv,
             int M, int N, int K) {
    __shared__ unsigned short As[2][128 * 32];   // 16 KB
    __shared__ unsigned short Bs[2][128 * 32];   // 16 KB

    const int t = threadIdx.x, lane = t & 63, wv = t >> 6;
    const int wm = wv >> 1, wn = wv & 1;
    const int m0 = blockIdx.y * 128, n0 = blockIdx.x * 128;
    const int fr = lane & 15, fg = lane >> 4;

    f32x4 acc[4][4];
    #pragma unroll
    for (int m = 0; m < 4; m++)
        #pragma unroll
        for (int n = 0; n < 4; n++)
            #pragma unroll
            for (int r = 0; r < 4; r++) acc[m][n][r] = 0.f;

#define GSTAGE(buf, kk)                                                               \
    {                                                                                 \
        _Pragma("unroll")                                                             \
        for (int i = 0; i < 2; i++) {                                                 \
            const int u = t + i * 256;                                                \
            const int row = u >> 2;                                                   \
            const int grp = (u & 3) ^ ((row ^ (row >> 2)) & 3);                       \
            gload16(A  + (size_t)(m0 + row) * K + (kk) + grp * 8,                     \
                    &As[buf][(i * 256 + wv * 64) * 8]);                               \
            gload16(BT + (size_t)(n0 + row) * K + (kk) + grp * 8,                     \
                    &Bs[buf][(i * 256 + wv * 64) * 8]);                               \
        }                                                                             \
    }

#define GCOMPUTE(buf)                                                                 \
    {                                                                                 \
        bf16x8 af[4], bfv[4];                                                         \
        _Pragma("unroll")                                                             \
        for (int m = 0; m < 4; m++) {                                                 \
            const int row = wm * 64 + m * 16 + fr;                                    \
            af[m] = *(const bf16x8*)&As[buf][row * 32 +                               \
                        ((fg ^ ((row ^ (row >> 2)) & 3)) << 3)];                      \
        }                                                                             \
        _Pragma("unroll")                                                             \
        for (int n = 0; n < 4; n++) {                                                 \
            const int row = wn * 64 + n * 16 + fr;                                    \
            bfv[n] = *(const bf16x8*)&Bs[buf][row * 32 +                              \
                        ((fg ^ ((row ^ (row >> 2)) & 3)) << 3)];                      \
        }                                                                             \
        __builtin_amdgcn_s_setprio(1);                                                \
        _Pragma("unroll")                                                             \
        for (int m = 0; m < 4; m++)                                                   \
            _Pragma("unroll")                                                         \
            for (int n = 0; n < 4; n++)                                               \
                acc[m][n] = __builtin_amdgcn_mfma_f32_16x16x32_bf16(                  \
                    af[m], bfv[n], acc[m][n], 0, 0, 0);                               \
        __builtin_amdgcn_s_setprio(0);                                                \
    }

    GSTAGE(0, 0);
    for (int k0 = 0; k0 < K; k0 += 64) {
        __syncthreads();               // drains stage of buf0 (k0); fences reads of buf1
        GSTAGE(1, k0 + 32);            // prefetch under compute of buf0
        GCOMPUTE(0);
        __syncthreads();               // drains stage of buf1; fences reads of buf0
        if (k0 + 64 < K) GSTAGE(0, k0 + 64);
        GCOMPUTE(1);
    }
#undef GSTAGE
#undef GCOMPUTE

    #pragma unroll
    for (int m = 0; m < 4; m++)
        #pragma unroll
        for (int n = 0; n < 4; n++) {
            const int col = n0 + wn * 64 + n * 16 + fr;
            const float bb = bias[col];
            #pragma unroll
            for (int rg = 0; rg < 4; rg++) {
                const int row = m0 + wm * 64 + m * 16 + fg * 4 + rg;
                const float v = acc[m][n][rg] + bb;
                if (MODE == 0) ((float*)Cv)[(size_t)row * N + col] = v;
                else ((unsigned short*)Cv)[(size_t)row * N + col] = f2bf(v);
            }
        }
}

// ---------------------------------------------------------------------------
// Causal MFMA flash attention: KVBLK=128, double-buffered, 1 barrier/tile.
// qkv bf16 [token][3072] (q at h*64, k at 1024+h*64), vT bf16 [bh][d][s].
// Block = 64 q rows (4 waves x 16), LPT order (qt descending).
// LDS 80 KB -> 2 blocks/CU; per-tile compute (~1300cy) >> HBM latency.
// ---------------------------------------------------------------------------
__global__ __launch_bounds__(256)
void attn_mfma(const unsigned short* __restrict__ qkvb, const unsigned short* __restrict__ vT,
               unsigned short* __restrict__ atto) {
    const int bx = blockIdx.x;
    const int qt = (NS / 64 - 1) - (bx >> 5);   // 31..0 (longest first)
    const int bh = bx & 31;
    const int h = bh & (NH - 1), b = bh >> 4;
    const int q0 = qt * 64;
    const int t = threadIdx.x, lane = t & 63, wv = t >> 6;
    const int fr = lane & 15, fg = lane >> 4;

    __shared__ unsigned short Kt[2][128 * 64];   // 32 KB
    __shared__ unsigned short Vt[2][64 * 128];   // 32 KB
    __shared__ unsigned short Ps[4][16 * 128];   // 16 KB, wave-private

    const unsigned short* kb = qkvb + (size_t)b * NS * RS + NDM + h * ND;
    const unsigned short* vb = vT + (size_t)bh * ND * NS;

    // Q fragments straight from global
    bf16x8 qf[2];
    {
        const unsigned short* qrow =
            qkvb + (size_t)(b * NS + q0 + wv * 16 + fr) * RS + h * ND;
        qf[0] = *(const bf16x8*)(qrow + fg * 8);
        qf[1] = *(const bf16x8*)(qrow + 32 + fg * 8);
    }

    f32x4 oacc[4];
    #pragma unroll
    for (int d = 0; d < 4; d++)
        #pragma unroll
        for (int r = 0; r < 4; r++) oacc[d][r] = 0.f;
    float mrow[4] = {-INFINITY, -INFINITY, -INFINITY, -INFINITY};
    float nmC[4]  = {INFINITY, INFINITY, INFINITY, INFINITY};    // -mrow*C1
    float lrow[4] = {0.f, 0.f, 0.f, 0.f};

    const int ntiles = (qt >> 1) + 1;    // tiles of 128 keys

#define STAGE_KV(cbuf, jtile)                                                        \
    {                                                                                \
        _Pragma("unroll")                                                            \
        for (int i = 0; i < 4; i++) {                                                \
            const int u = t + i * 256;                                               \
            const int row = u >> 3;                                                  \
            const int grp = (u & 7) ^ (row & 7);                                     \
            gload16(kb + (size_t)((jtile) * 128 + row) * RS + grp * 8,               \
                    &Kt[cbuf][(i * 256 + wv * 64) * 8]);                             \
        }                                                                            \
        _Pragma("unroll")                                                            \
        for (int i = 0; i < 4; i++) {                                                \
            const int u = t + i * 256;                                               \
            const int row = u >> 4;                                                  \
            const int grp = (u & 15) ^ (row & 7);                                    \
            gload16(vb + (size_t)row * NS + (jtile) * 128 + grp * 8,                 \
                    &Vt[cbuf][(i * 256 + wv * 64) * 8]);                             \
        }                                                                            \
    }

    STAGE_KV(0, 0);

    for (int jt = 0; jt < ntiles; jt++) {
        const int cur = jt & 1;
        __syncthreads();   // drains vmcnt (stage of cur done) + read-fence on cur^1
        if (jt + 1 < ntiles) STAGE_KV(cur ^ 1, jt + 1);
        const unsigned short* Ktc = Kt[cur];
        const unsigned short* Vtc = Vt[cur];

        // ---- S = Q K^T : 8 key-blocks x 2 k-halves
        f32x4 sacc[8];
        __builtin_amdgcn_s_setprio(1);
        #pragma unroll
        for (int kbi = 0; kbi < 8; kbi++) {
            #pragma unroll
            for (int r = 0; r < 4; r++) sacc[kbi][r] = 0.f;
            const int row = kbi * 16 + fr;
            const bf16x8 kf0 = *(const bf16x8*)&Ktc[row * 64 + (((fg) ^ (row & 7)) << 3)];
            const bf16x8 kf1 = *(const bf16x8*)&Ktc[row * 64 + (((4 + fg) ^ (row & 7)) << 3)];
            sacc[kbi] = __builtin_amdgcn_mfma_f32_16x16x32_bf16(qf[0], kf0, sacc[kbi], 0, 0, 0);
            sacc[kbi] = __builtin_amdgcn_mfma_f32_16x16x32_bf16(qf[1], kf1, sacc[kbi], 0, 0, 0);
        }
        __builtin_amdgcn_s_setprio(0);

        if (jt == ntiles - 1) {   // only the last tile can cross the diagonal
            #pragma unroll
            for (int kbi = 0; kbi < 8; kbi++) {
                const int keyg = jt * 128 + kbi * 16 + fr;
                #pragma unroll
                for (int reg = 0; reg < 4; reg++) {
                    const int qg = q0 + wv * 16 + fg * 4 + reg;
                    if (keyg > qg) sacc[kbi][reg] = -INFINITY;
                }
            }
        }

        // ---- online softmax (exp2 domain, defer-max)
        float pmax[4];
        #pragma unroll
        for (int reg = 0; reg < 4; reg++) {
            float pm = fmaxf(fmaxf(fmaxf(sacc[0][reg], sacc[1][reg]),
                                   fmaxf(sacc[2][reg], sacc[3][reg])),
                             fmaxf(fmaxf(sacc[4][reg], sacc[5][reg]),
                                   fmaxf(sacc[6][reg], sacc[7][reg])));
            pm = fmaxf(pm, __shfl_xor(pm, 1));
            pm = fmaxf(pm, __shfl_xor(pm, 2));
            pm = fmaxf(pm, __shfl_xor(pm, 4));
            pm = fmaxf(pm, __shfl_xor(pm, 8));
            pmax[reg] = pm;
        }
        bool need = false;
        #pragma unroll
        for (int reg = 0; reg < 4; reg++) need |= (pmax[reg] > mrow[reg] + THR_RAW);
        if (__any(need)) {
            #pragma unroll
            for (int reg = 0; reg < 4; reg++) {
                const float mn = fmaxf(mrow[reg], pmax[reg]);
                const float alpha = __builtin_amdgcn_exp2f((mrow[reg] - mn) * C1);
                mrow[reg] = mn;
                nmC[reg] = -mn * C1;
                lrow[reg] *= alpha;
                #pragma unroll
                for (int dblk = 0; dblk < 4; dblk++) oacc[dblk][reg] *= alpha;
            }
        }
        #pragma unroll
        for (int reg = 0; reg < 4; reg++) {
            float ps = 0.f;
            #pragma unroll
            for (int kbi = 0; kbi < 8; kbi++) {
                const float p = __builtin_amdgcn_exp2f(fmaf(sacc[kbi][reg], C1, nmC[reg]));
                sacc[kbi][reg] = p;
                ps += p;
            }
            ps += __shfl_xor(ps, 1);
            ps += __shfl_xor(ps, 2);
            ps += __shfl_xor(ps, 4);
            ps += __shfl_xor(ps, 8);
            lrow[reg] += ps;
        }

        // ---- P -> wave-private LDS (swizzled like Vt rows)
        #pragma unroll
        for (int kbi = 0; kbi < 8; kbi++) {
            const int colk = kbi * 16 + fr;
            #pragma unroll
            for (int reg = 0; reg < 4; reg++) {
                const int prow = fg * 4 + reg;
                Ps[wv][prow * 128 + (((colk >> 3) ^ (prow & 7)) << 3) + (colk & 7)] =
                    f2bf(sacc[kbi][reg]);
            }
        }

        // ---- O += P V  (Ps wave-private: in-order ds, no barrier)
        bf16x8 pf[4];
        #pragma unroll
        for (int ks = 0; ks < 4; ks++)
            pf[ks] = *(const bf16x8*)&Ps[wv][fr * 128 + (((ks * 4 + fg) ^ (fr & 7)) << 3)];
        __builtin_amdgcn_s_setprio(1);
        #pragma unroll
        for (int dblk = 0; dblk < 4; dblk++) {
            const int vrow = dblk * 16 + fr;
            #pragma unroll
            for (int ks = 0; ks < 4; ks++) {
                const bf16x8 vf =
                    *(const bf16x8*)&Vtc[vrow * 128 + (((ks * 4 + fg) ^ (vrow & 7)) << 3)];
                oacc[dblk] = __builtin_amdgcn_mfma_f32_16x16x32_bf16(
                    pf[ks], vf, oacc[dblk], 0, 0, 0);
            }
        }
        __builtin_amdgcn_s_setprio(0);
    }
#undef STAGE_KV

    // ---- epilogue
    #pragma unroll
    for (int reg = 0; reg < 4; reg++) {
        const float inv = 1.f / lrow[reg];
        const int row = q0 + wv * 16 + fg * 4 + reg;
        unsigned short* dst = atto + ((size_t)b * NS + row) * NDM + h * ND;
        #pragma unroll
        for (int dblk = 0; dblk < 4; dblk++)
            dst[dblk * 16 + fr] = f2bf(oacc[dblk][reg] * inv);
    }
}

// ---------------------------------------------------------------------------
extern "C" void kernel_launch(void* const* d_in, const int* in_sizes, int n_in,
                              void* d_out, int out_size, void* d_ws, size_t ws_size,
                              hipStream_t stream) {
    const float* x     = (const float*)d_in[0];
    const float* w_qkv = (const float*)d_in[1];
    const float* b_qkv = (const float*)d_in[2];
    const float* w_out = (const float*)d_in[3];
    const float* b_out = (const float*)d_in[4];
    float* out = (float*)d_out;

    unsigned short* xb   = (unsigned short*)d_ws;             //  8 MB [4096][1024] (aliased by atto)
    unsigned short* wqT  = xb   + (size_t)NM * NDM;           //  6 MB [3072][1024]
    unsigned short* woT  = wqT  + (size_t)3 * NDM * NDM;      //  2 MB [1024][1024]
    unsigned short* qkvb = woT  + (size_t)NDM * NDM;          // 24 MB [4096][3072]
    unsigned short* vT   = qkvb + (size_t)NM * 3 * NDM;       //  8 MB [32][64][2048]
    unsigned short* atto = xb;                                //  alias: xb dead after gemm1

    convert_bf16<<<2048, 256, 0, stream>>>(x, xb, NM * NDM / 8);
    transpose_bf16<<<dim3(3 * NDM / 64, NDM / 64), 256, 0, stream>>>(w_qkv, wqT, NDM, 3 * NDM);
    transpose_bf16<<<dim3(NDM / 64, NDM / 64), 256, 0, stream>>>(w_out, woT, NDM, NDM);

    // 1) qkv = x @ w_qkv + b   (bf16, row-major, coalesced)
    gemm128<1><<<dim3(3 * NDM / 128, NM / 128), 256, 0, stream>>>(
        xb, wqT, b_qkv, qkvb, NM, 3 * NDM, NDM);

    // 1b) vT = transpose of v columns
    vtrans<<<dim3(NS / 64, NB * NH), 256, 0, stream>>>(qkvb, vT);

    // 2) causal MFMA flash attention (KVBLK=128, double-buffered)
    attn_mfma<<<dim3((NS / 64) * NB * NH), 256, 0, stream>>>(qkvb, vT, atto);

    // 3) out = atto @ w_out + b  (fp32 out)
    gemm128<0><<<dim3(NDM / 128, NM / 128), 256, 0, stream>>>(
        atto, woT, b_out, out, NM, NDM, NDM);
}

// Round 7
// 185.213 us; speedup vs baseline: 1.1634x; 1.1117x over previous
//
#include <hip/hip_runtime.h>
#include <hip/hip_bf16.h>

#define NB 2
#define NS 2048
#define NDM 1024
#define NH 16
#define ND 64
#define NM (NB * NS)   // 4096
#define RS 3072        // qkv row stride
#define C1 0.1803368801111243f   // SCALE * log2(e)
#define THR_RAW 44.36141956f     // 8 / C1 : defer-max threshold in raw-score units

typedef __attribute__((ext_vector_type(8))) short bf16x8;   // MFMA A/B frag (4 VGPRs)
typedef __attribute__((ext_vector_type(4))) float f32x4;    // MFMA C/D frag

__device__ __forceinline__ unsigned short f2bf(float f) {
    unsigned int u = __float_as_uint(f);
    u += 0x7fffu + ((u >> 16) & 1u);   // RNE
    return (unsigned short)(u >> 16);
}

// async global->LDS, 16B per lane. LDS dest = wave-uniform base + lane*16.
__device__ __forceinline__ void gload16(const unsigned short* g, unsigned short* l) {
    __builtin_amdgcn_global_load_lds(
        (const __attribute__((address_space(1))) void*)g,
        (__attribute__((address_space(3))) void*)l, 16, 0, 0);
}

// ---------------------------------------------------------------------------
// fp32 -> bf16 elementwise
// ---------------------------------------------------------------------------
__global__ __launch_bounds__(256)
void convert_bf16(const float* __restrict__ in, unsigned short* __restrict__ out, int n8) {
    int i = blockIdx.x * 256 + threadIdx.x;
    const int stride = gridDim.x * 256;
    for (; i < n8; i += stride) {
        const float4 a = ((const float4*)in)[i * 2];
        const float4 b = ((const float4*)in)[i * 2 + 1];
        bf16x8 v;
        v[0] = (short)f2bf(a.x); v[1] = (short)f2bf(a.y);
        v[2] = (short)f2bf(a.z); v[3] = (short)f2bf(a.w);
        v[4] = (short)f2bf(b.x); v[5] = (short)f2bf(b.y);
        v[6] = (short)f2bf(b.z); v[7] = (short)f2bf(b.w);
        *(bf16x8*)(out + (size_t)i * 8) = v;
    }
}

// ---------------------------------------------------------------------------
// W[K][N] fp32 -> WT[N][K] bf16 (64x64 LDS-tiled)
// ---------------------------------------------------------------------------
__global__ __launch_bounds__(256)
void transpose_bf16(const float* __restrict__ W, unsigned short* __restrict__ WT,
                    int K, int N) {
    __shared__ float Ts[64][65];
    const int n0 = blockIdx.x * 64, k0 = blockIdx.y * 64;
    const int t = threadIdx.x;
    {
        const int c4 = (t & 15) * 4;
        #pragma unroll
        for (int p = 0; p < 4; p++) {
            const int r = (t >> 4) + p * 16;
            const float4 v = *(const float4*)(W + (size_t)(k0 + r) * N + n0 + c4);
            Ts[r][c4] = v.x; Ts[r][c4 + 1] = v.y; Ts[r][c4 + 2] = v.z; Ts[r][c4 + 3] = v.w;
        }
    }
    __syncthreads();
    {
        const int cc8 = (t & 7) * 8;
        #pragma unroll
        for (int p = 0; p < 2; p++) {
            const int rr = (t >> 3) + p * 32;
            bf16x8 v;
            #pragma unroll
            for (int j = 0; j < 8; j++) v[j] = (short)f2bf(Ts[cc8 + j][rr]);
            *(bf16x8*)(WT + (size_t)(n0 + rr) * K + k0 + cc8) = v;
        }
    }
}

// ---------------------------------------------------------------------------
// V columns of qkv [token][3072] -> vT [bh][d=64][s=2048], 64x64 tiles.
// ---------------------------------------------------------------------------
__global__ __launch_bounds__(256)
void vtrans(const unsigned short* __restrict__ qkvb, unsigned short* __restrict__ vT) {
    __shared__ unsigned short Ts[64][65];
    const int st = blockIdx.x, bh = blockIdx.y;
    const int h = bh & (NH - 1), b = bh >> 4;
    const int t = threadIdx.x;
    {
        const int c8 = (t & 7) * 8;
        #pragma unroll
        for (int p = 0; p < 2; p++) {
            const int r = (t >> 3) + p * 32;
            const unsigned short* src =
                qkvb + (size_t)(b * NS + st * 64 + r) * RS + 2 * NDM + h * ND + c8;
            const bf16x8 v = *(const bf16x8*)src;
            #pragma unroll
            for (int j = 0; j < 8; j++) Ts[r][c8 + j] = (unsigned short)v[j];
        }
    }
    __syncthreads();
    {
        #pragma unroll
        for (int i = 0; i < 2; i++) {
            const int u = t + i * 256;
            const int d = u >> 3, cg = (u & 7) * 8;
            bf16x8 v;
            #pragma unroll
            for (int j = 0; j < 8; j++) v[j] = (short)Ts[cg + j][d];
            *(bf16x8*)(vT + ((size_t)bh * ND + d) * NS + st * 64 + cg) = v;
        }
    }
}

// ---------------------------------------------------------------------------
// 128x128 GEMM, BK=32, double-buffered (1 barrier/K-step). bf16 in.
// MODE 0: fp32 C + bias. MODE 1: bf16 C + bias.
// ---------------------------------------------------------------------------
template<int MODE>
__global__ __launch_bounds__(256)
void gemm128(const unsigned short* __restrict__ A, const unsigned short* __restrict__ BT,
             const float* __restrict__ bias, void* __restrict__ Cv,
             int M, int N, int K) {
    __shared__ unsigned short As[2][128 * 32];
    __shared__ unsigned short Bs[2][128 * 32];

    const int t = threadIdx.x, lane = t & 63, wv = t >> 6;
    const int wm = wv >> 1, wn = wv & 1;
    const int m0 = blockIdx.y * 128, n0 = blockIdx.x * 128;
    const int fr = lane & 15, fg = lane >> 4;

    f32x4 acc[4][4];
    #pragma unroll
    for (int m = 0; m < 4; m++)
        #pragma unroll
        for (int n = 0; n < 4; n++)
            #pragma unroll
            for (int r = 0; r < 4; r++) acc[m][n][r] = 0.f;

#define GSTAGE(buf, kk)                                                               \
    {                                                                                 \
        _Pragma("unroll")                                                             \
        for (int i = 0; i < 2; i++) {                                                 \
            const int u = t + i * 256;                                                \
            const int row = u >> 2;                                                   \
            const int grp = (u & 3) ^ ((row ^ (row >> 2)) & 3);                       \
            gload16(A  + (size_t)(m0 + row) * K + (kk) + grp * 8,                     \
                    &As[buf][(i * 256 + wv * 64) * 8]);                               \
            gload16(BT + (size_t)(n0 + row) * K + (kk) + grp * 8,                     \
                    &Bs[buf][(i * 256 + wv * 64) * 8]);                               \
        }                                                                             \
    }

#define GCOMPUTE(buf)                                                                 \
    {                                                                                 \
        bf16x8 af[4], bfv[4];                                                         \
        _Pragma("unroll")                                                             \
        for (int m = 0; m < 4; m++) {                                                 \
            const int row = wm * 64 + m * 16 + fr;                                    \
            af[m] = *(const bf16x8*)&As[buf][row * 32 +                               \
                        ((fg ^ ((row ^ (row >> 2)) & 3)) << 3)];                      \
        }                                                                             \
        _Pragma("unroll")                                                             \
        for (int n = 0; n < 4; n++) {                                                 \
            const int row = wn * 64 + n * 16 + fr;                                    \
            bfv[n] = *(const bf16x8*)&Bs[buf][row * 32 +                              \
                        ((fg ^ ((row ^ (row >> 2)) & 3)) << 3)];                      \
        }                                                                             \
        __builtin_amdgcn_s_setprio(1);                                                \
        _Pragma("unroll")                                                             \
        for (int m = 0; m < 4; m++)                                                   \
            _Pragma("unroll")                                                         \
            for (int n = 0; n < 4; n++)                                               \
                acc[m][n] = __builtin_amdgcn_mfma_f32_16x16x32_bf16(                  \
                    af[m], bfv[n], acc[m][n], 0, 0, 0);                               \
        __builtin_amdgcn_s_setprio(0);                                                \
    }

    GSTAGE(0, 0);
    for (int k0 = 0; k0 < K; k0 += 64) {
        __syncthreads();
        GSTAGE(1, k0 + 32);
        GCOMPUTE(0);
        __syncthreads();
        if (k0 + 64 < K) GSTAGE(0, k0 + 64);
        GCOMPUTE(1);
    }
#undef GSTAGE
#undef GCOMPUTE

    #pragma unroll
    for (int m = 0; m < 4; m++)
        #pragma unroll
        for (int n = 0; n < 4; n++) {
            const int col = n0 + wn * 64 + n * 16 + fr;
            const float bb = bias[col];
            #pragma unroll
            for (int rg = 0; rg < 4; rg++) {
                const int row = m0 + wm * 64 + m * 16 + fg * 4 + rg;
                const float v = acc[m][n][rg] + bb;
                if (MODE == 0) ((float*)Cv)[(size_t)row * N + col] = v;
                else ((unsigned short*)Cv)[(size_t)row * N + col] = f2bf(v);
            }
        }
}

// ---------------------------------------------------------------------------
// 128x64 GEMM (for N-small gemm2: doubles blocks/CU vs 128x128).
// fp32 C + bias. Same double-buffer/swizzle structure, BN=64.
// ---------------------------------------------------------------------------
__global__ __launch_bounds__(256)
void gemm128x64(const unsigned short* __restrict__ A, const unsigned short* __restrict__ BT,
                const float* __restrict__ bias, float* __restrict__ C,
                int M, int N, int K) {
    __shared__ unsigned short As[2][128 * 32];   // 16 KB
    __shared__ unsigned short Bs[2][64 * 32];    //  8 KB

    const int t = threadIdx.x, lane = t & 63, wv = t >> 6;
    const int wm = wv >> 1, wn = wv & 1;
    const int m0 = blockIdx.y * 128, n0 = blockIdx.x * 64;
    const int fr = lane & 15, fg = lane >> 4;

    f32x4 acc[4][2];
    #pragma unroll
    for (int m = 0; m < 4; m++)
        #pragma unroll
        for (int n = 0; n < 2; n++)
            #pragma unroll
            for (int r = 0; r < 4; r++) acc[m][n][r] = 0.f;

#define G2STAGE(buf, kk)                                                              \
    {                                                                                 \
        _Pragma("unroll")                                                             \
        for (int i = 0; i < 2; i++) {                                                 \
            const int u = t + i * 256;                                                \
            const int row = u >> 2;                                                   \
            const int grp = (u & 3) ^ ((row ^ (row >> 2)) & 3);                       \
            gload16(A + (size_t)(m0 + row) * K + (kk) + grp * 8,                      \
                    &As[buf][(i * 256 + wv * 64) * 8]);                               \
        }                                                                             \
        {                                                                             \
            const int row = t >> 2;                                                   \
            const int grp = (t & 3) ^ ((row ^ (row >> 2)) & 3);                       \
            gload16(BT + (size_t)(n0 + row) * K + (kk) + grp * 8,                     \
                    &Bs[buf][(wv * 64) * 8]);                                         \
        }                                                                             \
    }

#define G2COMPUTE(buf)                                                                \
    {                                                                                 \
        bf16x8 af[4], bfv[2];                                                         \
        _Pragma("unroll")                                                             \
        for (int m = 0; m < 4; m++) {                                                 \
            const int row = wm * 64 + m * 16 + fr;                                    \
            af[m] = *(const bf16x8*)&As[buf][row * 32 +                               \
                        ((fg ^ ((row ^ (row >> 2)) & 3)) << 3)];                      \
        }                                                                             \
        _Pragma("unroll")                                                             \
        for (int n = 0; n < 2; n++) {                                                 \
            const int row = wn * 32 + n * 16 + fr;                                    \
            bfv[n] = *(const bf16x8*)&Bs[buf][row * 32 +                              \
                        ((fg ^ ((row ^ (row >> 2)) & 3)) << 3)];                      \
        }                                                                             \
        __builtin_amdgcn_s_setprio(1);                                                \
        _Pragma("unroll")                                                             \
        for (int m = 0; m < 4; m++)                                                   \
            _Pragma("unroll")                                                         \
            for (int n = 0; n < 2; n++)                                               \
                acc[m][n] = __builtin_amdgcn_mfma_f32_16x16x32_bf16(                  \
                    af[m], bfv[n], acc[m][n], 0, 0, 0);                               \
        __builtin_amdgcn_s_setprio(0);                                                \
    }

    G2STAGE(0, 0);
    for (int k0 = 0; k0 < K; k0 += 64) {
        __syncthreads();
        G2STAGE(1, k0 + 32);
        G2COMPUTE(0);
        __syncthreads();
        if (k0 + 64 < K) G2STAGE(0, k0 + 64);
        G2COMPUTE(1);
    }
#undef G2STAGE
#undef G2COMPUTE

    #pragma unroll
    for (int m = 0; m < 4; m++)
        #pragma unroll
        for (int n = 0; n < 2; n++) {
            const int col = n0 + wn * 32 + n * 16 + fr;
            const float bb = bias[col];
            #pragma unroll
            for (int rg = 0; rg < 4; rg++) {
                const int row = m0 + wm * 64 + m * 16 + fg * 4 + rg;
                C[(size_t)row * N + col] = acc[m][n][rg] + bb;
            }
        }
}

// ---------------------------------------------------------------------------
// Causal MFMA flash attention with SWAPPED QK^T (S^T = mfma(K,Q)): each lane
// holds the 32 S-values of ONE q-row (q = lane&15) -> in-lane softmax with
// only 2 shfl per reduction, cvt_pk_bf16 packing, b32 P-writes (conflict-free
// by row-XOR swizzle). KVBLK=128, double-buffered, 1 barrier/tile, LPT order.
// ---------------------------------------------------------------------------
__global__ __launch_bounds__(256)
void attn_mfma(const unsigned short* __restrict__ qkvb, const unsigned short* __restrict__ vT,
               unsigned short* __restrict__ atto) {
    const int bx = blockIdx.x;
    const int qt = (NS / 64 - 1) - (bx >> 5);   // 31..0 (longest first)
    const int bh = bx & 31;
    const int h = bh & (NH - 1), b = bh >> 4;
    const int q0 = qt * 64;
    const int t = threadIdx.x, lane = t & 63, wv = t >> 6;
    const int fr = lane & 15, fg = lane >> 4;

    __shared__ unsigned short Kt[2][128 * 64];   // 32 KB
    __shared__ unsigned short Vt[2][64 * 128];   // 32 KB
    __shared__ unsigned short Ps[4][16 * 128];   // 16 KB, wave-private

    const unsigned short* kb = qkvb + (size_t)b * NS * RS + NDM + h * ND;
    const unsigned short* vb = vT + (size_t)bh * ND * NS;

    // Q fragments straight from global (row = fr -> q-row, d-slice = fg*8)
    bf16x8 qf[2];
    {
        const unsigned short* qrow =
            qkvb + (size_t)(b * NS + q0 + wv * 16 + fr) * RS + h * ND;
        qf[0] = *(const bf16x8*)(qrow + fg * 8);
        qf[1] = *(const bf16x8*)(qrow + 32 + fg * 8);
    }

    f32x4 oacc[4];
    #pragma unroll
    for (int d = 0; d < 4; d++)
        #pragma unroll
        for (int r = 0; r < 4; r++) oacc[d][r] = 0.f;
    float mrow = -INFINITY;    // running max of raw scores for q = fr (replicated over fg)
    float nmC  = INFINITY;     // -mrow*C1
    float lrow = 0.f;

    const int ntiles = (qt >> 1) + 1;    // tiles of 128 keys

#define STAGE_KV(cbuf, jtile)                                                        \
    {                                                                                \
        _Pragma("unroll")                                                            \
        for (int i = 0; i < 4; i++) {                                                \
            const int u = t + i * 256;                                               \
            const int row = u >> 3;                                                  \
            const int grp = (u & 7) ^ (row & 7);                                     \
            gload16(kb + (size_t)((jtile) * 128 + row) * RS + grp * 8,               \
                    &Kt[cbuf][(i * 256 + wv * 64) * 8]);                             \
        }                                                                            \
        _Pragma("unroll")                                                            \
        for (int i = 0; i < 4; i++) {                                                \
            const int u = t + i * 256;                                               \
            const int row = u >> 4;                                                  \
            const int grp = (u & 15) ^ (row & 7);                                    \
            gload16(vb + (size_t)row * NS + (jtile) * 128 + grp * 8,                 \
                    &Vt[cbuf][(i * 256 + wv * 64) * 8]);                             \
        }                                                                            \
    }

    STAGE_KV(0, 0);

    for (int jt = 0; jt < ntiles; jt++) {
        const int cur = jt & 1;
        __syncthreads();   // drains vmcnt (stage of cur done) + read-fence on cur^1
        if (jt + 1 < ntiles) STAGE_KV(cur ^ 1, jt + 1);
        const unsigned short* Ktc = Kt[cur];
        const unsigned short* Vtc = Vt[cur];

        // ---- S^T = K Q^T : sacc[kbi][reg] = S[key=kbi*16+fg*4+reg][q=fr]
        f32x4 sacc[8];
        __builtin_amdgcn_s_setprio(1);
        #pragma unroll
        for (int kbi = 0; kbi < 8; kbi++) {
            #pragma unroll
            for (int r = 0; r < 4; r++) sacc[kbi][r] = 0.f;
            const int row = kbi * 16 + fr;
            const bf16x8 kf0 = *(const bf16x8*)&Ktc[row * 64 + (((fg) ^ (row & 7)) << 3)];
            const bf16x8 kf1 = *(const bf16x8*)&Ktc[row * 64 + (((4 + fg) ^ (row & 7)) << 3)];
            sacc[kbi] = __builtin_amdgcn_mfma_f32_16x16x32_bf16(kf0, qf[0], sacc[kbi], 0, 0, 0);
            sacc[kbi] = __builtin_amdgcn_mfma_f32_16x16x32_bf16(kf1, qf[1], sacc[kbi], 0, 0, 0);
        }
        __builtin_amdgcn_s_setprio(0);

        if (jt == ntiles - 1) {   // only the last tile can cross the diagonal
            const int qg = q0 + wv * 16 + fr;
            #pragma unroll
            for (int kbi = 0; kbi < 8; kbi++) {
                #pragma unroll
                for (int reg = 0; reg < 4; reg++) {
                    const int keyg = jt * 128 + kbi * 16 + fg * 4 + reg;
                    if (keyg > qg) sacc[kbi][reg] = -INFINITY;
                }
            }
        }

        // ---- in-lane row max (32 values) + 2-shfl cross-group reduce
        float mk[8];
        #pragma unroll
        for (int kbi = 0; kbi < 8; kbi++)
            mk[kbi] = fmaxf(fmaxf(sacc[kbi][0], sacc[kbi][1]),
                            fmaxf(sacc[kbi][2], sacc[kbi][3]));
        float pm = fmaxf(fmaxf(fmaxf(mk[0], mk[1]), fmaxf(mk[2], mk[3])),
                         fmaxf(fmaxf(mk[4], mk[5]), fmaxf(mk[6], mk[7])));
        pm = fmaxf(pm, __shfl_xor(pm, 16));
        pm = fmaxf(pm, __shfl_xor(pm, 32));

        // ---- defer-max: rescale only when the row max moved by > THR
        if (__any(pm > mrow + THR_RAW)) {
            const float mn = fmaxf(mrow, pm);
            const float alpha = __builtin_amdgcn_exp2f((mrow - mn) * C1);
            mrow = mn;
            nmC = -mn * C1;
            lrow *= alpha;
            #pragma unroll
            for (int reg = 0; reg < 4; reg++) {
                const float aq = __shfl(alpha, fg * 4 + reg);   // alpha of q = fg*4+reg
                #pragma unroll
                for (int dblk = 0; dblk < 4; dblk++) oacc[dblk][reg] *= aq;
            }
        }

        // ---- P = exp2(S*C1 - m*C1), in-lane sum + 2 shfl
        float psum = 0.f;
        #pragma unroll
        for (int kbi = 0; kbi < 8; kbi++) {
            #pragma unroll
            for (int reg = 0; reg < 4; reg++) {
                const float p = __builtin_amdgcn_exp2f(fmaf(sacc[kbi][reg], C1, nmC));
                sacc[kbi][reg] = p;
                psum += p;
            }
        }
        psum += __shfl_xor(psum, 16);
        psum += __shfl_xor(psum, 32);
        lrow += psum;

        // ---- P row (q=fr) -> wave-private LDS: cvt_pk + b32 writes (swizzled)
        #pragma unroll
        for (int kbi = 0; kbi < 8; kbi++) {
            unsigned int w0, w1;
            asm("v_cvt_pk_bf16_f32 %0, %1, %2"
                : "=v"(w0) : "v"(sacc[kbi][0]), "v"(sacc[kbi][1]));
            asm("v_cvt_pk_bf16_f32 %0, %1, %2"
                : "=v"(w1) : "v"(sacc[kbi][2]), "v"(sacc[kbi][3]));
            const int grp = (kbi * 2 + (fg >> 1)) ^ (fr & 7);
            const int base = fr * 128 + grp * 8 + (fg & 1) * 4;   // shorts, b32-aligned
            *(unsigned int*)&Ps[wv][base]     = w0;   // k+0, k+1
            *(unsigned int*)&Ps[wv][base + 2] = w1;   // k+2, k+3
        }

        // ---- O += P V  (Ps wave-private: in-order ds, no barrier)
        bf16x8 pf[4];
        #pragma unroll
        for (int ks = 0; ks < 4; ks++)
            pf[ks] = *(const bf16x8*)&Ps[wv][fr * 128 + (((ks * 4 + fg) ^ (fr & 7)) << 3)];
        __builtin_amdgcn_s_setprio(1);
        #pragma unroll
        for (int dblk = 0; dblk < 4; dblk++) {
            const int vrow = dblk * 16 + fr;
            #pragma unroll
            for (int ks = 0; ks < 4; ks++) {
                const bf16x8 vf =
                    *(const bf16x8*)&Vtc[vrow * 128 + (((ks * 4 + fg) ^ (vrow & 7)) << 3)];
                oacc[dblk] = __builtin_amdgcn_mfma_f32_16x16x32_bf16(
                    pf[ks], vf, oacc[dblk], 0, 0, 0);
            }
        }
        __builtin_amdgcn_s_setprio(0);
    }
#undef STAGE_KV

    // ---- epilogue: O[q=fg*4+reg][d=dblk*16+fr] / l(q)
    const float rl = 1.f / lrow;    // for q = fr
    #pragma unroll
    for (int reg = 0; reg < 4; reg++) {
        const float inv = __shfl(rl, fg * 4 + reg);
        const int row = q0 + wv * 16 + fg * 4 + reg;
        unsigned short* dst = atto + ((size_t)b * NS + row) * NDM + h * ND;
        #pragma unroll
        for (int dblk = 0; dblk < 4; dblk++)
            dst[dblk * 16 + fr] = f2bf(oacc[dblk][reg] * inv);
    }
}

// ---------------------------------------------------------------------------
extern "C" void kernel_launch(void* const* d_in, const int* in_sizes, int n_in,
                              void* d_out, int out_size, void* d_ws, size_t ws_size,
                              hipStream_t stream) {
    const float* x     = (const float*)d_in[0];
    const float* w_qkv = (const float*)d_in[1];
    const float* b_qkv = (const float*)d_in[2];
    const float* w_out = (const float*)d_in[3];
    const float* b_out = (const float*)d_in[4];
    float* out = (float*)d_out;

    unsigned short* xb   = (unsigned short*)d_ws;             //  8 MB (aliased by atto)
    unsigned short* wqT  = xb   + (size_t)NM * NDM;           //  6 MB [3072][1024]
    unsigned short* woT  = wqT  + (size_t)3 * NDM * NDM;      //  2 MB [1024][1024]
    unsigned short* qkvb = woT  + (size_t)NDM * NDM;          // 24 MB [4096][3072]
    unsigned short* vT   = qkvb + (size_t)NM * 3 * NDM;       //  8 MB [32][64][2048]
    unsigned short* atto = xb;                                //  alias: xb dead after gemm1

    convert_bf16<<<2048, 256, 0, stream>>>(x, xb, NM * NDM / 8);
    transpose_bf16<<<dim3(3 * NDM / 64, NDM / 64), 256, 0, stream>>>(w_qkv, wqT, NDM, 3 * NDM);
    transpose_bf16<<<dim3(NDM / 64, NDM / 64), 256, 0, stream>>>(w_out, woT, NDM, NDM);

    // 1) qkv = x @ w_qkv + b   (bf16, row-major)
    gemm128<1><<<dim3(3 * NDM / 128, NM / 128), 256, 0, stream>>>(
        xb, wqT, b_qkv, qkvb, NM, 3 * NDM, NDM);

    // 1b) vT = transpose of v columns
    vtrans<<<dim3(NS / 64, NB * NH), 256, 0, stream>>>(qkvb, vT);

    // 2) causal MFMA flash attention (swapped QK^T, in-lane softmax)
    attn_mfma<<<dim3((NS / 64) * NB * NH), 256, 0, stream>>>(qkvb, vT, atto);

    // 3) out = atto @ w_out + b  (fp32 out, 128x64 tiles -> 2 blocks/CU)
    gemm128x64<<<dim3(NDM / 64, NM / 128), 256, 0, stream>>>(
        atto, woT, b_out, out, NM, NDM, NDM);
}